// Round 1
// 251.480 us; speedup vs baseline: 1.0033x; 1.0033x over previous
//
#include <hip/hip_runtime.h>

// Problem constants (match reference):
//   x:       [256, 3, 224, 224] fp32
//   patch:   [1, 3, 30, 30]     fp32
//   offsets: [256, 2]           int32, each in [0, 194)
//   out = x with patch added at per-sample (r, c).
#define ISIZE 224
#define PSIZE 30
#define BATCH 256
#define NCH   3

typedef float f32x4 __attribute__((ext_vector_type(4)));

// Exact decomposition (no remainders):
//   floats/channel = 224*224 = 50176 -> 12544 float4 -> 49 blocks of 256 thr
//   blocks/image   = 3*49    = 147;  grid = (147, 256)
// b = blockIdx.y and ch = blockIdx.x/49 are uniform -> offsets are s_loads,
// patch-intersection test is one scalar branch; ~85% of blocks are a pure
// load -> store stream.
//
// R1 change vs previous best: drop the __builtin_nontemporal_* hints.
// The harness restores x right before the timed kernel, so much of x is
// L3-resident; nt loads force those reads out to HBM and nt stores skip
// the L2/L3 write path the 6.5 TB/s fill kernel uses. Plain cached
// accesses mirror the 6.29 TB/s float4-copy microbenchmark exactly.

__global__ __launch_bounds__(256)
void RandomPrompter_64982855189232_kernel(const float* __restrict__ x,
                                          const float* __restrict__ patch,
                                          const int* __restrict__ offsets,
                                          float* __restrict__ out) {
    constexpr int PER_ROW4    = ISIZE / 4;                // 56
    constexpr int BLK_PER_CH  = ISIZE * ISIZE / 4 / 256;  // 49
    constexpr int BLK_PER_IMG = NCH * BLK_PER_CH;         // 147

    const int bx  = blockIdx.x;   // [0,147) — position within image
    const int b   = blockIdx.y;   // [0,256) — batch index (uniform)
    const int tid = threadIdx.x;

    const int i4 = (b * BLK_PER_IMG + bx) * 256 + tid;

    const f32x4* __restrict__ x4 = (const f32x4*)x;
    f32x4* __restrict__ o4 = (f32x4*)out;

    // Plain cached load: x may be L3-resident from the harness restore.
    f32x4 v = x4[i4];

    const int ch       = bx / BLK_PER_CH;                 // uniform
    const int blk_base = (bx - ch * BLK_PER_CH) * 256;    // uniform
    const int rem2     = blk_base + tid;                  // [0,12544) in channel

    // Uniform scalar loads (address depends only on blockIdx.y).
    const int r = offsets[2 * b];
    const int c = offsets[2 * b + 1];

    // Block-uniform intersection test on the rows this block covers.
    const int row_lo = blk_base / PER_ROW4;
    const int row_hi = (blk_base + 255) / PER_ROW4;

    if (row_hi >= r && row_lo < r + PSIZE) {
        const int row = rem2 / PER_ROW4;
        const int col = (rem2 - row * PER_ROW4) * 4;
        const int pr  = row - r;
        if (pr >= 0 && pr < PSIZE) {
            // Patch is tiny (10.8 KB) and reused by many blocks: cached loads.
            const float* __restrict__ prow = patch + (ch * PSIZE + pr) * PSIZE;
#pragma unroll
            for (int j = 0; j < 4; ++j) {
                const int pc = col + j - c;
                if (pc >= 0 && pc < PSIZE) v[j] += prow[pc];
            }
        }
    }
    // Plain cached store.
    o4[i4] = v;
}

extern "C" void kernel_launch(void* const* d_in, const int* in_sizes, int n_in,
                              void* d_out, int out_size, void* d_ws, size_t ws_size,
                              hipStream_t stream) {
    const float* x       = (const float*)d_in[0];
    const float* patch   = (const float*)d_in[1];
    const int*   offsets = (const int*)d_in[2];
    float*       out     = (float*)d_out;

    dim3 grid(NCH * (ISIZE * ISIZE / 4 / 256), BATCH);  // (147, 256)
    dim3 block(256);

    RandomPrompter_64982855189232_kernel<<<grid, block, 0, stream>>>(x, patch, offsets, out);
}